// Round 13
// baseline (109.534 us; speedup 1.0000x reference)
//
#include <hip/hip_runtime.h>
#include <math.h>

constexpr int B = 2, C = 16, H = 128, W = 128;
constexpr int HW = H * W;

// xpad: [B,16,146,148]; orig (h,w) -> (h+9, w+9); pads zeroed by conv1
constexpr int XR = 146, XS = 148, XCH = XR * XS;
constexpr size_t XPAD_ELEMS = (size_t)B * C * XCH;

// ypad: [B,16,130,136]; orig (h,w) -> (h+1, w+4); pads zeroed by kpn19
constexpr int YR = 130, YS = 136, YCH = YR * YS;

__device__ __forceinline__ float4 ld4(const float* p) { return *(const float4*)p; }

// ===========================================================================
// kpn19 (FROZEN from round 12 — first version to escape the 50 µs floor):
// wave = 64 px lanes (256B coalesced kern loads), 4 waves = 4 ch-groups
// reading IDENTICAL kern addresses (L1 broadcast). Per kh: 19 independent
// scalar kern loads (kv[19]) -> fence -> 76 x-loads + 76 FMAs. Low VGPR
// pressure -> allocator neither sinks nor spills the batch.
// ===========================================================================
__global__ __launch_bounds__(256) void kpn19(
    const float* __restrict__ xpad,  // [B,16,146,148]
    const float* __restrict__ kern,  // [B,361,128,128]
    float* __restrict__ ypad)        // [B,16,130,136]
{
    int tid  = threadIdx.x;
    int lane = tid & 63;
    int cg   = tid >> 6;             // wave-uniform, 0..3
    int blk  = blockIdx.x;           // 512 = wb2 x h128 x b2
    int wb   = blk & 1;
    int h    = (blk >> 1) & 127;
    int b    = blk >> 8;
    int px   = wb * 64 + lane;
    int c0   = cg * 4;

    // ---- ypad pad zeroing (replaces memset) ----
    if (tid < 64) {
        int pl = tid >> 2, i = tid & 3;
        int col = wb ? 132 + i : i;
        ypad[((size_t)(b * C + pl) * YR + (h + 1)) * YS + col] = 0.f;
    }
    if (h == 0 || h == 127) {
        int r = (h == 0) ? 0 : 129;
        for (int f = tid; f < 1088; f += 256) {
            int pl = f / 68, col = wb * 68 + f % 68;
            ypad[((size_t)(b * C + pl) * YR + r) * YS + col] = 0.f;
        }
    }

    const float* kp = kern + (size_t)b * 361 * HW + (size_t)h * W + px;
    const float* x0 = xpad + (size_t)(b * C + c0) * XCH + (size_t)h * XS + px;

    float a0 = 0.f, a1 = 0.f, a2 = 0.f, a3 = 0.f;

    for (int kh = 0; kh < 19; ++kh) {
        float kv[19];
        const float* kpr = kp + (size_t)(kh * 19) * HW;
        #pragma unroll
        for (int kw = 0; kw < 19; ++kw)
            kv[kw] = kpr[(size_t)kw * HW];
        __builtin_amdgcn_sched_barrier(0);

        const float* xr = x0 + (size_t)kh * XS;
        #pragma unroll
        for (int kw = 0; kw < 19; ++kw) {
            float k = kv[kw];
            a0 = fmaf(xr[kw],            k, a0);
            a1 = fmaf(xr[kw + XCH],      k, a1);
            a2 = fmaf(xr[kw + 2 * XCH],  k, a2);
            a3 = fmaf(xr[kw + 3 * XCH],  k, a3);
        }
    }

    float* yp = ypad + ((size_t)(b * C + c0) * YR + (h + 1)) * YS + (px + 4);
    yp[0]       = a0;
    yp[YCH]     = a1;
    yp[2 * YCH] = a2;
    yp[3 * YCH] = a3;
}

// ===========================================================================
// conv1: 3x3 conv (pad 1) + exact GELU -> xpad. LDS row-staging (r10-proven):
// 3 rows x 16 ic staged once per block as float4 (24 wave-VMEM instr vs 144
// scalar per thread), taps become conflict-free ds_read. Thread = 1 px x 4 oc.
// Block = 128 px x 2 ocg; grid = half2 x h128 x b2 = 512.
// ===========================================================================
__global__ __launch_bounds__(256) void conv1_gelu(
    const float* __restrict__ in, const float* __restrict__ w1,
    const float* __restrict__ b1, float* __restrict__ xpad)
{
    __shared__ float ws[2304];
    __shared__ float bs[16];
    __shared__ __align__(16) float xs[16][3][128];   // 24 KB

    int tid = threadIdx.x;
    for (int i = tid; i < 2304; i += 256) ws[i] = w1[i];
    if (tid < 16) bs[tid] = b1[tid];

    int px  = tid & 127;
    int ocg = tid >> 7;                  // wave-uniform
    int blk = blockIdx.x;                // 512 = half2 x h128 x b2
    int half = blk & 1;
    int h   = (blk >> 1) & 127;
    int b   = blk >> 8;
    int oc0 = half * 8 + ocg * 4;

    // ---- xpad pad zeroing for the 8 planes this block owns ----
    if (tid < 160) {
        int j = tid / 20, i = tid % 20;
        int col = (i < 9) ? i : 128 + i;             // 0..8, 137..147
        xpad[((size_t)(b * C + half * 8 + j) * XR + (h + 9)) * XS + col] = 0.f;
    }
    if (h == 0 || h == 127) {
        int r0 = (h == 0) ? 0 : 137;
        for (int f = tid; f < 8 * 9 * XS; f += 256) {
            int j = f / (9 * XS), rem = f % (9 * XS);
            int r = r0 + rem / XS, col = rem % XS;
            xpad[((size_t)(b * C + half * 8 + j) * XR + r) * XS + col] = 0.f;
        }
    }

    // ---- stage rows h-1..h+1 x 16 ic into LDS (coalesced float4) ----
    const float4 z4 = make_float4(0.f, 0.f, 0.f, 0.f);
    #pragma unroll
    for (int j = 0; j < 6; ++j) {
        int m = tid + j * 256;           // < 1536
        int ic = m / 96, rem = m - ic * 96, r = rem >> 5, q = rem & 31;
        int row = h + r - 1;
        float4 v = ((unsigned)row < 128u)
                 ? ld4(in + ((size_t)(b * C + ic) * H + row) * W + q * 4) : z4;
        *(float4*)&xs[ic][r][q * 4] = v;
    }
    __syncthreads();

    bool wm = (px > 0), wp = (px < 127);
    float a0 = 0.f, a1 = 0.f, a2 = 0.f, a3 = 0.f;

    #pragma unroll
    for (int ic = 0; ic < 16; ++ic) {
        float t[9];
        #pragma unroll
        for (int r = 0; r < 3; ++r) {
            t[r * 3 + 0] = wm ? xs[ic][r][px - 1] : 0.f;
            t[r * 3 + 1] = xs[ic][r][px];
            t[r * 3 + 2] = wp ? xs[ic][r][px + 1] : 0.f;
        }
        #pragma unroll
        for (int j = 0; j < 4; ++j) {
            const float* wp9 = ws + (oc0 + j) * 144 + ic * 9;
            float s = fmaf(wp9[0], t[0], fmaf(wp9[1], t[1], fmaf(wp9[2], t[2],
                      fmaf(wp9[3], t[3], fmaf(wp9[4], t[4], fmaf(wp9[5], t[5],
                      fmaf(wp9[6], t[6], fmaf(wp9[7], t[7], wp9[8] * t[8]))))))));
            if (j == 0) a0 += s; else if (j == 1) a1 += s;
            else if (j == 2) a2 += s; else a3 += s;
        }
    }

    float* xp = xpad + ((size_t)(b * C + oc0) * XR + (h + 9)) * XS + (px + 9);
    float v;
    v = a0 + bs[oc0 + 0]; xp[0]       = 0.5f * v * (1.0f + erff(v * 0.70710678f));
    v = a1 + bs[oc0 + 1]; xp[XCH]     = 0.5f * v * (1.0f + erff(v * 0.70710678f));
    v = a2 + bs[oc0 + 2]; xp[2 * XCH] = 0.5f * v * (1.0f + erff(v * 0.70710678f));
    v = a3 + bs[oc0 + 3]; xp[3 * XCH] = 0.5f * v * (1.0f + erff(v * 0.70710678f));
}

// ===========================================================================
// conv2: 3x3 conv (pad 1) + sigmoid -> out. LDS row-staging (r10-proven),
// padded-y input so taps are unconditional. Same geometry as conv1.
// ===========================================================================
__global__ __launch_bounds__(256) void conv2_sig(
    const float* __restrict__ ypad, const float* __restrict__ w2,
    const float* __restrict__ b2, float* __restrict__ out)
{
    __shared__ float ws[2304];
    __shared__ float bs[16];
    __shared__ __align__(16) float ys[16][3][136];   // 26.1 KB

    int tid = threadIdx.x;
    for (int i = tid; i < 2304; i += 256) ws[i] = w2[i];
    if (tid < 16) bs[tid] = b2[tid];

    int px  = tid & 127;
    int ocg = tid >> 7;
    int blk = blockIdx.x;                // 512 = half2 x h128 x b2
    int half = blk & 1;
    int h   = (blk >> 1) & 127;
    int b   = blk >> 8;
    int oc0 = half * 8 + ocg * 4;

    // stage padded rows h..h+2 x 16 ic, cols 0..135
    #pragma unroll
    for (int j = 0; j < 7; ++j) {
        int m = tid + j * 256;
        if (m < 1632) {
            int ic = m / 102, rem = m - ic * 102, r = rem / 34, q = rem % 34;
            float4 v = ld4(ypad + ((size_t)(b * C + ic) * YR + (h + r)) * YS + q * 4);
            *(float4*)&ys[ic][r][q * 4] = v;
        }
    }
    __syncthreads();

    float a0 = 0.f, a1 = 0.f, a2 = 0.f, a3 = 0.f;

    #pragma unroll
    for (int ic = 0; ic < 16; ++ic) {
        float t[9];
        #pragma unroll
        for (int r = 0; r < 3; ++r) {
            t[r * 3 + 0] = ys[ic][r][px + 3];
            t[r * 3 + 1] = ys[ic][r][px + 4];
            t[r * 3 + 2] = ys[ic][r][px + 5];
        }
        #pragma unroll
        for (int j = 0; j < 4; ++j) {
            const float* wp9 = ws + (oc0 + j) * 144 + ic * 9;
            float s = fmaf(wp9[0], t[0], fmaf(wp9[1], t[1], fmaf(wp9[2], t[2],
                      fmaf(wp9[3], t[3], fmaf(wp9[4], t[4], fmaf(wp9[5], t[5],
                      fmaf(wp9[6], t[6], fmaf(wp9[7], t[7], wp9[8] * t[8]))))))));
            if (j == 0) a0 += s; else if (j == 1) a1 += s;
            else if (j == 2) a2 += s; else a3 += s;
        }
    }

    float* op = out + ((size_t)(b * C + oc0) * H + h) * W + px;
    float v;
    v = a0 + bs[oc0 + 0]; op[0]      = 1.0f / (1.0f + expf(-v));
    v = a1 + bs[oc0 + 1]; op[HW]     = 1.0f / (1.0f + expf(-v));
    v = a2 + bs[oc0 + 2]; op[2 * HW] = 1.0f / (1.0f + expf(-v));
    v = a3 + bs[oc0 + 3]; op[3 * HW] = 1.0f / (1.0f + expf(-v));
}

// ---------------------------------------------------------------------------
extern "C" void kernel_launch(void* const* d_in, const int* in_sizes, int n_in,
                              void* d_out, int out_size, void* d_ws, size_t ws_size,
                              hipStream_t stream)
{
    const float* input  = (const float*)d_in[0];
    const float* kernel = (const float*)d_in[1];
    const float* w1     = (const float*)d_in[2];
    const float* b1     = (const float*)d_in[3];
    const float* w2     = (const float*)d_in[4];
    const float* b2     = (const float*)d_in[5];
    float* out = (float*)d_out;

    float* xpad = (float*)d_ws;
    float* ypad = xpad + XPAD_ELEMS;

    conv1_gelu<<<512, 256, 0, stream>>>(input, w1, b1, xpad);
    kpn19<<<512, 256, 0, stream>>>(xpad, kernel, ypad);
    conv2_sig<<<512, 256, 0, stream>>>(ypad, w2, b2, out);
}

// Round 15
// 64.578 us; speedup vs baseline: 1.6961x; 1.6961x over previous
//
#include <hip/hip_runtime.h>
#include <math.h>

constexpr int B = 2, C = 16, H = 128, W = 128;
constexpr int HW = H * W;

// xpad: [B,16,146,148]; orig (h,w) -> (h+9, w+9); pads zeroed by conv1
constexpr int XR = 146, XS = 148, XCH = XR * XS;
constexpr size_t XPAD_ELEMS = (size_t)B * C * XCH;

// ypad: [B,16,130,136]; orig (h,w) -> (h+1, w+4); pads zeroed by kpn19
constexpr int YR = 130, YS = 136, YCH = YR * YS;

// ===========================================================================
// kpn19: r12's winning kv[19] scalar-batch loop, kh split into 4 quarters
// WITHIN a 1024-thread block (no extra workspace — r14's abort was d_ws
// overflow from a second ypad buffer).
// Block = 64 px-lanes x 4 cg x 4 q = 1024 thr (16 waves). Grid = wb2 x h128
// x b2 = 512 -> 2 blocks/CU -> up to 32 waves/CU (4x r12 TLP).
// q owns kh rows q*5..q*5+4 (q3: 4 rows); kern/x traffic unchanged (disjoint
// rows). Quarters 1-3 deposit partials in 12 KB LDS; q0 reduces + writes y.
// ===========================================================================
__global__ __launch_bounds__(1024) void kpn19(
    const float* __restrict__ xpad,  // [B,16,146,148]
    const float* __restrict__ kern,  // [B,361,128,128]
    float* __restrict__ ypad)        // [B,16,130,136]
{
    __shared__ float red[3][16][64];   // 12 KB

    int tid  = threadIdx.x;
    int lane = tid & 63;
    int cg   = (tid >> 6) & 3;
    int q    = tid >> 8;             // wave-uniform kh-quarter, 0..3
    int blk  = blockIdx.x;           // 512 = wb2 x h128 x b2
    int wb   = blk & 1;
    int h    = (blk >> 1) & 127;
    int b    = blk >> 8;
    int px   = wb * 64 + lane;
    int c0   = cg * 4;

    // ---- ypad pad zeroing (replaces memset) ----
    if (tid < 64) {
        int pl = tid >> 2, i = tid & 3;
        int col = wb ? 132 + i : i;
        ypad[((size_t)(b * C + pl) * YR + (h + 1)) * YS + col] = 0.f;
    }
    if (h == 0 || h == 127) {
        int r = (h == 0) ? 0 : 129;
        for (int f = tid; f < 1088; f += 1024) {
            int pl = f / 68, col = wb * 68 + f % 68;
            ypad[((size_t)(b * C + pl) * YR + r) * YS + col] = 0.f;
        }
    }

    const float* kp = kern + (size_t)b * 361 * HW + (size_t)h * W + px;
    const float* x0 = xpad + (size_t)(b * C + c0) * XCH + (size_t)h * XS + px;

    float a0 = 0.f, a1 = 0.f, a2 = 0.f, a3 = 0.f;

    int kh0 = q * 5;
    int nkh = (q == 3) ? 4 : 5;

    for (int khh = 0; khh < nkh; ++khh) {
        int kh = kh0 + khh;
        // --- batch: 19 independent coalesced kern loads (one kh row) ---
        float kv[19];
        const float* kpr = kp + (size_t)(kh * 19) * HW;
        #pragma unroll
        for (int kw = 0; kw < 19; ++kw)
            kv[kw] = kpr[(size_t)kw * HW];
        __builtin_amdgcn_sched_barrier(0);
        // --- compute: x taps (L2-resident) x kern row ---
        const float* xr = x0 + (size_t)kh * XS;
        #pragma unroll
        for (int kw = 0; kw < 19; ++kw) {
            float k = kv[kw];
            a0 = fmaf(xr[kw],           k, a0);
            a1 = fmaf(xr[kw + XCH],     k, a1);
            a2 = fmaf(xr[kw + 2 * XCH], k, a2);
            a3 = fmaf(xr[kw + 3 * XCH], k, a3);
        }
    }

    // ---- reduce quarters via LDS (conflict-free: lanes -> consecutive) ----
    if (q > 0) {
        red[q - 1][c0 + 0][lane] = a0;
        red[q - 1][c0 + 1][lane] = a1;
        red[q - 1][c0 + 2][lane] = a2;
        red[q - 1][c0 + 3][lane] = a3;
    }
    __syncthreads();
    if (q == 0) {
        #pragma unroll
        for (int j = 0; j < 3; ++j) {
            a0 += red[j][c0 + 0][lane];
            a1 += red[j][c0 + 1][lane];
            a2 += red[j][c0 + 2][lane];
            a3 += red[j][c0 + 3][lane];
        }
        float* yp = ypad + ((size_t)(b * C + c0) * YR + (h + 1)) * YS + (px + 4);
        yp[0]       = a0;
        yp[YCH]     = a1;
        yp[2 * YCH] = a2;
        yp[3 * YCH] = a3;
    }
}

// ===========================================================================
// conv1: 3x3 conv (pad 1) + exact GELU -> xpad. r12 structure + register cap
// __launch_bounds__(256,4) (VGPR <= 128, 4 waves/SIMD) + unroll 4 keeps load
// batches ~36 (sink-safe, spill-free regime). Thread = 1 px x 2 oc.
// Grid = ocq4 x h128 x b2 = 1024. Zeroes xpad pads.
// ===========================================================================
__global__ __launch_bounds__(256, 4) void conv1_gelu(
    const float* __restrict__ in, const float* __restrict__ w1,
    const float* __restrict__ b1, float* __restrict__ xpad)
{
    __shared__ float ws[2304];
    __shared__ float bs[16];
    for (int i = threadIdx.x; i < 2304; i += 256) ws[i] = w1[i];
    if (threadIdx.x < 16) bs[threadIdx.x] = b1[threadIdx.x];
    __syncthreads();

    int px  = threadIdx.x & 127;
    int opg = threadIdx.x >> 7;          // wave-uniform
    int blk = blockIdx.x;                // 1024 = ocq4 x h128 x b2
    int ocq = blk & 3;
    int h   = (blk >> 2) & 127;
    int b   = blk >> 9;
    int oc0 = ocq * 4 + opg * 2;

    // xpad pad zeroing: col pads of row h+9 for this block's 4 planes
    if (threadIdx.x < 80) {
        int j = threadIdx.x / 20, i = threadIdx.x % 20;
        int col = (i < 9) ? i : 128 + i;             // 0..8, 137..147
        xpad[((size_t)(b * C + ocq * 4 + j) * XR + (h + 9)) * XS + col] = 0.f;
    }
    if (h == 0 || h == 127) {
        int r0 = (h == 0) ? 0 : 137;
        for (int f = threadIdx.x; f < 4 * 9 * XS; f += 256) {
            int j = f / (9 * XS), rem = f % (9 * XS);
            int r = r0 + rem / XS, col = rem % XS;
            xpad[((size_t)(b * C + ocq * 4 + j) * XR + r) * XS + col] = 0.f;
        }
    }

    const float* inb = in + (size_t)b * C * HW;
    bool hm = (h > 0), hp = (h < 127), wm = (px > 0), wp = (px < 127);

    float a0 = 0.f, a1 = 0.f;
    #pragma unroll 4
    for (int ic = 0; ic < 16; ++ic) {
        const float* p0 = inb + (size_t)ic * HW + (size_t)h * W + px;
        float t0 = (hm && wm) ? p0[-W - 1] : 0.f;
        float t1 = hm         ? p0[-W]     : 0.f;
        float t2 = (hm && wp) ? p0[-W + 1] : 0.f;
        float t3 = wm         ? p0[-1]     : 0.f;
        float t4 =              p0[0];
        float t5 = wp         ? p0[1]      : 0.f;
        float t6 = (hp && wm) ? p0[W - 1]  : 0.f;
        float t7 = hp         ? p0[W]      : 0.f;
        float t8 = (hp && wp) ? p0[W + 1]  : 0.f;
        #pragma unroll
        for (int j = 0; j < 2; ++j) {
            const float* wp9 = ws + (oc0 + j) * 144 + ic * 9;
            float s = fmaf(wp9[0], t0, fmaf(wp9[1], t1, fmaf(wp9[2], t2,
                      fmaf(wp9[3], t3, fmaf(wp9[4], t4, fmaf(wp9[5], t5,
                      fmaf(wp9[6], t6, fmaf(wp9[7], t7, wp9[8] * t8))))))));
            if (j == 0) a0 += s; else a1 += s;
        }
    }

    float* xp = xpad + ((size_t)(b * C + oc0) * XR + (h + 9)) * XS + (px + 9);
    float v;
    v = a0 + bs[oc0 + 0]; xp[0]   = 0.5f * v * (1.0f + erff(v * 0.70710678f));
    v = a1 + bs[oc0 + 1]; xp[XCH] = 0.5f * v * (1.0f + erff(v * 0.70710678f));
}

// ===========================================================================
// conv2: 3x3 conv (pad 1) + sigmoid -> out. Register-capped like conv1;
// single ypad. Thread = 1 px x 2 oc; grid = ocq4 x h128 x b2 = 1024.
// ===========================================================================
__global__ __launch_bounds__(256, 4) void conv2_sig(
    const float* __restrict__ ypad, const float* __restrict__ w2,
    const float* __restrict__ b2, float* __restrict__ out)
{
    __shared__ float ws[2304];
    __shared__ float bs[16];
    for (int i = threadIdx.x; i < 2304; i += 256) ws[i] = w2[i];
    if (threadIdx.x < 16) bs[threadIdx.x] = b2[threadIdx.x];
    __syncthreads();

    int px  = threadIdx.x & 127;
    int opg = threadIdx.x >> 7;
    int blk = blockIdx.x;                // 1024 = ocq4 x h128 x b2
    int ocq = blk & 3;
    int h   = (blk >> 2) & 127;
    int b   = blk >> 9;
    int oc0 = ocq * 4 + opg * 2;

    float a0 = 0.f, a1 = 0.f;
    #pragma unroll 4
    for (int ic = 0; ic < 16; ++ic) {
        const float* p0 = ypad + ((size_t)(b * C + ic) * YR + (h + 1)) * YS + (px + 4);
        float t0 = p0[-YS - 1], t1 = p0[-YS], t2 = p0[-YS + 1];
        float t3 = p0[-1],      t4 = p0[0],   t5 = p0[1];
        float t6 = p0[YS - 1],  t7 = p0[YS],  t8 = p0[YS + 1];
        #pragma unroll
        for (int j = 0; j < 2; ++j) {
            const float* wp9 = ws + (oc0 + j) * 144 + ic * 9;
            float s = fmaf(wp9[0], t0, fmaf(wp9[1], t1, fmaf(wp9[2], t2,
                      fmaf(wp9[3], t3, fmaf(wp9[4], t4, fmaf(wp9[5], t5,
                      fmaf(wp9[6], t6, fmaf(wp9[7], t7, wp9[8] * t8))))))));
            if (j == 0) a0 += s; else a1 += s;
        }
    }

    float* op = out + ((size_t)(b * C + oc0) * H + h) * W + px;
    float v;
    v = a0 + bs[oc0 + 0]; op[0]  = 1.0f / (1.0f + expf(-v));
    v = a1 + bs[oc0 + 1]; op[HW] = 1.0f / (1.0f + expf(-v));
}

// ---------------------------------------------------------------------------
extern "C" void kernel_launch(void* const* d_in, const int* in_sizes, int n_in,
                              void* d_out, int out_size, void* d_ws, size_t ws_size,
                              hipStream_t stream)
{
    const float* input  = (const float*)d_in[0];
    const float* kernel = (const float*)d_in[1];
    const float* w1     = (const float*)d_in[2];
    const float* b1     = (const float*)d_in[3];
    const float* w2     = (const float*)d_in[4];
    const float* b2     = (const float*)d_in[5];
    float* out = (float*)d_out;

    float* xpad = (float*)d_ws;
    float* ypad = xpad + XPAD_ELEMS;     // same footprint as rounds 1-13

    conv1_gelu<<<1024, 256, 0, stream>>>(input, w1, b1, xpad);
    kpn19<<<512, 1024, 0, stream>>>(xpad, kernel, ypad);
    conv2_sig<<<1024, 256, 0, stream>>>(ypad, w2, b2, out);
}

// Round 16
// 58.008 us; speedup vs baseline: 1.8883x; 1.1133x over previous
//
#include <hip/hip_runtime.h>
#include <math.h>

constexpr int B = 2, C = 16, H = 128, W = 128;
constexpr int HW = H * W;

// xpad: [B,16,146,148]; orig (h,w) -> (h+9, w+9); pads zeroed by conv1
constexpr int XR = 146, XS = 148, XCH = XR * XS;
constexpr size_t XPAD_ELEMS = (size_t)B * C * XCH;

// ypad: [B,16,130,136]; orig (h,w) -> (h+1, w+4); pads zeroed by kpn19
constexpr int YR = 130, YS = 136, YCH = YR * YS;

// ===========================================================================
// kpn19: r15 q-split skeleton + r12 kv[19] kern batch, with the 76 x-tap
// VMEM reads per wave-row moved to the LDS pipe (x staged once per row via
// global_load_lds, double-buffered per q). Kills ~757 MB of L1 re-read
// traffic (the 19x overlapping-window amplification); kern stays on the
// register/VMEM path (189 MB, L1-broadcast across the 4 cg waves).
// Block = 64 px-lanes x 4 cg x 4 q = 1024 thr; grid = wb2 x h128 x b2 = 512
// (2 blocks/CU, 32 waves). LDS: xls[4 q][2 buf][16 ch][84] + red = 55 KB.
// Stage/row = 336 float4 chunks per q-group (2 exec-masked gll per thread);
// vmcnt(0)+__syncthreads once per row (no counted-vmcnt fragility).
// ===========================================================================
__global__ __launch_bounds__(1024) void kpn19(
    const float* __restrict__ xpad,  // [B,16,146,148]
    const float* __restrict__ kern,  // [B,361,128,128]
    float* __restrict__ ypad)        // [B,16,130,136]
{
    __shared__ __align__(16) float xls[4][2][16][84];   // 43,008 B
    __shared__ float red[3][16][64];                    // 12,288 B

    int tid  = threadIdx.x;
    int lane = tid & 63;
    int wq   = (tid >> 6) & 3;       // wave within q == channel group
    int q    = tid >> 8;             // kh-quarter, wave-uniform
    int blk  = blockIdx.x;           // 512 = wb2 x h128 x b2
    int wb   = blk & 1;
    int h    = (blk >> 1) & 127;
    int b    = blk >> 8;
    int px   = wb * 64 + lane;
    int c0   = wq * 4;

    // ---- ypad pad zeroing (replaces memset) ----
    if (tid < 64) {
        int pl = tid >> 2, i = tid & 3;
        int col = wb ? 132 + i : i;
        ypad[((size_t)(b * C + pl) * YR + (h + 1)) * YS + col] = 0.f;
    }
    if (h == 0 || h == 127) {
        int r = (h == 0) ? 0 : 129;
        for (int f = tid; f < 1088; f += 1024) {
            int pl = f / 68, col = wb * 68 + f % 68;
            ypad[((size_t)(b * C + pl) * YR + r) * YS + col] = 0.f;
        }
    }

    // ---- x staging sources: q-group covers 336 chunks = [16 ch][21 col4] ----
    int idx = tid & 255;                 // position within q-group
    int ma  = idx;                       // chunk a (always valid, < 336)
    int mb  = idx + 256;                 // chunk b (valid if < 336)
    bool vb = (mb < 336);
    int ca  = ma / 21, cola = ma % 21;
    int cb  = vb ? mb / 21 : 0, colb = vb ? mb % 21 : 0;
    int kh0 = q * 5;
    int nkh = (q == 3) ? 4 : 5;

    const float* sa = xpad + (size_t)(b * C + ca) * XCH
                      + (size_t)(h + kh0) * XS + wb * 64 + cola * 4;
    const float* sb = xpad + (size_t)(b * C + cb) * XCH
                      + (size_t)(h + kh0) * XS + wb * 64 + colb * 4;

    const float* kp = kern + (size_t)b * 361 * HW + (size_t)h * W + px;

    float a0 = 0.f, a1 = 0.f, a2 = 0.f, a3 = 0.f;

#define STAGE(bufsel)                                                         \
    {                                                                         \
        __builtin_amdgcn_global_load_lds((const void*)sa,                     \
            (void*)(&xls[q][bufsel][0][0] + wq * 256), 16, 0, 0);             \
        if (vb)                                                               \
            __builtin_amdgcn_global_load_lds((const void*)sb,                 \
                (void*)(&xls[q][bufsel][0][0] + 1024 + wq * 256), 16, 0, 0);  \
        sa += XS; sb += XS;                                                   \
    }

    // Prologue: stage row 0 into buf 0.
    STAGE(0);
    asm volatile("s_waitcnt vmcnt(0)" ::: "memory");
    __syncthreads();

    #pragma unroll
    for (int r = 0; r < 5; ++r) {
        const int cur = r & 1;
        if (r + 1 < nkh) STAGE(cur ^ 1);          // wave-uniform predicate
        if (r < nkh) {
            int kh = kh0 + r;
            // --- kern batch: 19 independent coalesced loads (r12 winner) ---
            float kv[19];
            const float* kpr = kp + (size_t)(kh * 19) * HW;
            #pragma unroll
            for (int kw = 0; kw < 19; ++kw)
                kv[kw] = kpr[(size_t)kw * HW];
            __builtin_amdgcn_sched_barrier(0);
            // --- taps from LDS (stride-4B lanes -> conflict-free) ---
            #pragma unroll
            for (int kw = 0; kw < 19; ++kw) {
                float k = kv[kw];
                a0 = fmaf(xls[q][cur][c0 + 0][lane + kw], k, a0);
                a1 = fmaf(xls[q][cur][c0 + 1][lane + kw], k, a1);
                a2 = fmaf(xls[q][cur][c0 + 2][lane + kw], k, a2);
                a3 = fmaf(xls[q][cur][c0 + 3][lane + kw], k, a3);
            }
        }
        asm volatile("s_waitcnt vmcnt(0)" ::: "memory");
        __syncthreads();
    }
#undef STAGE

    // ---- reduce quarters via LDS; q0 writes y ----
    if (q > 0) {
        red[q - 1][c0 + 0][lane] = a0;
        red[q - 1][c0 + 1][lane] = a1;
        red[q - 1][c0 + 2][lane] = a2;
        red[q - 1][c0 + 3][lane] = a3;
    }
    __syncthreads();
    if (q == 0) {
        #pragma unroll
        for (int j = 0; j < 3; ++j) {
            a0 += red[j][c0 + 0][lane];
            a1 += red[j][c0 + 1][lane];
            a2 += red[j][c0 + 2][lane];
            a3 += red[j][c0 + 3][lane];
        }
        float* yp = ypad + ((size_t)(b * C + c0) * YR + (h + 1)) * YS + (px + 4);
        yp[0]       = a0;
        yp[YCH]     = a1;
        yp[2 * YCH] = a2;
        yp[3 * YCH] = a3;
    }
}

// ===========================================================================
// conv1 (FROZEN r15): 3x3 conv + exact GELU -> xpad. __launch_bounds__(256,4)
// caps VGPR at 128; unroll 4 keeps batches ~36 (spill-free regime).
// ===========================================================================
__global__ __launch_bounds__(256, 4) void conv1_gelu(
    const float* __restrict__ in, const float* __restrict__ w1,
    const float* __restrict__ b1, float* __restrict__ xpad)
{
    __shared__ float ws[2304];
    __shared__ float bs[16];
    for (int i = threadIdx.x; i < 2304; i += 256) ws[i] = w1[i];
    if (threadIdx.x < 16) bs[threadIdx.x] = b1[threadIdx.x];
    __syncthreads();

    int px  = threadIdx.x & 127;
    int opg = threadIdx.x >> 7;          // wave-uniform
    int blk = blockIdx.x;                // 1024 = ocq4 x h128 x b2
    int ocq = blk & 3;
    int h   = (blk >> 2) & 127;
    int b   = blk >> 9;
    int oc0 = ocq * 4 + opg * 2;

    if (threadIdx.x < 80) {
        int j = threadIdx.x / 20, i = threadIdx.x % 20;
        int col = (i < 9) ? i : 128 + i;             // 0..8, 137..147
        xpad[((size_t)(b * C + ocq * 4 + j) * XR + (h + 9)) * XS + col] = 0.f;
    }
    if (h == 0 || h == 127) {
        int r0 = (h == 0) ? 0 : 137;
        for (int f = threadIdx.x; f < 4 * 9 * XS; f += 256) {
            int j = f / (9 * XS), rem = f % (9 * XS);
            int r = r0 + rem / XS, col = rem % XS;
            xpad[((size_t)(b * C + ocq * 4 + j) * XR + r) * XS + col] = 0.f;
        }
    }

    const float* inb = in + (size_t)b * C * HW;
    bool hm = (h > 0), hp = (h < 127), wm = (px > 0), wp = (px < 127);

    float a0 = 0.f, a1 = 0.f;
    #pragma unroll 4
    for (int ic = 0; ic < 16; ++ic) {
        const float* p0 = inb + (size_t)ic * HW + (size_t)h * W + px;
        float t0 = (hm && wm) ? p0[-W - 1] : 0.f;
        float t1 = hm         ? p0[-W]     : 0.f;
        float t2 = (hm && wp) ? p0[-W + 1] : 0.f;
        float t3 = wm         ? p0[-1]     : 0.f;
        float t4 =              p0[0];
        float t5 = wp         ? p0[1]      : 0.f;
        float t6 = (hp && wm) ? p0[W - 1]  : 0.f;
        float t7 = hp         ? p0[W]      : 0.f;
        float t8 = (hp && wp) ? p0[W + 1]  : 0.f;
        #pragma unroll
        for (int j = 0; j < 2; ++j) {
            const float* wp9 = ws + (oc0 + j) * 144 + ic * 9;
            float s = fmaf(wp9[0], t0, fmaf(wp9[1], t1, fmaf(wp9[2], t2,
                      fmaf(wp9[3], t3, fmaf(wp9[4], t4, fmaf(wp9[5], t5,
                      fmaf(wp9[6], t6, fmaf(wp9[7], t7, wp9[8] * t8))))))));
            if (j == 0) a0 += s; else a1 += s;
        }
    }

    float* xp = xpad + ((size_t)(b * C + oc0) * XR + (h + 9)) * XS + (px + 9);
    float v;
    v = a0 + bs[oc0 + 0]; xp[0]   = 0.5f * v * (1.0f + erff(v * 0.70710678f));
    v = a1 + bs[oc0 + 1]; xp[XCH] = 0.5f * v * (1.0f + erff(v * 0.70710678f));
}

// ===========================================================================
// conv2 (FROZEN r15): 3x3 conv + sigmoid -> out.
// ===========================================================================
__global__ __launch_bounds__(256, 4) void conv2_sig(
    const float* __restrict__ ypad, const float* __restrict__ w2,
    const float* __restrict__ b2, float* __restrict__ out)
{
    __shared__ float ws[2304];
    __shared__ float bs[16];
    for (int i = threadIdx.x; i < 2304; i += 256) ws[i] = w2[i];
    if (threadIdx.x < 16) bs[threadIdx.x] = b2[threadIdx.x];
    __syncthreads();

    int px  = threadIdx.x & 127;
    int opg = threadIdx.x >> 7;
    int blk = blockIdx.x;                // 1024 = ocq4 x h128 x b2
    int ocq = blk & 3;
    int h   = (blk >> 2) & 127;
    int b   = blk >> 9;
    int oc0 = ocq * 4 + opg * 2;

    float a0 = 0.f, a1 = 0.f;
    #pragma unroll 4
    for (int ic = 0; ic < 16; ++ic) {
        const float* p0 = ypad + ((size_t)(b * C + ic) * YR + (h + 1)) * YS + (px + 4);
        float t0 = p0[-YS - 1], t1 = p0[-YS], t2 = p0[-YS + 1];
        float t3 = p0[-1],      t4 = p0[0],   t5 = p0[1];
        float t6 = p0[YS - 1],  t7 = p0[YS],  t8 = p0[YS + 1];
        #pragma unroll
        for (int j = 0; j < 2; ++j) {
            const float* wp9 = ws + (oc0 + j) * 144 + ic * 9;
            float s = fmaf(wp9[0], t0, fmaf(wp9[1], t1, fmaf(wp9[2], t2,
                      fmaf(wp9[3], t3, fmaf(wp9[4], t4, fmaf(wp9[5], t5,
                      fmaf(wp9[6], t6, fmaf(wp9[7], t7, wp9[8] * t8))))))));
            if (j == 0) a0 += s; else a1 += s;
        }
    }

    float* op = out + ((size_t)(b * C + oc0) * H + h) * W + px;
    float v;
    v = a0 + bs[oc0 + 0]; op[0]  = 1.0f / (1.0f + expf(-v));
    v = a1 + bs[oc0 + 1]; op[HW] = 1.0f / (1.0f + expf(-v));
}

// ---------------------------------------------------------------------------
extern "C" void kernel_launch(void* const* d_in, const int* in_sizes, int n_in,
                              void* d_out, int out_size, void* d_ws, size_t ws_size,
                              hipStream_t stream)
{
    const float* input  = (const float*)d_in[0];
    const float* kernel = (const float*)d_in[1];
    const float* w1     = (const float*)d_in[2];
    const float* b1     = (const float*)d_in[3];
    const float* w2     = (const float*)d_in[4];
    const float* b2     = (const float*)d_in[5];
    float* out = (float*)d_out;

    float* xpad = (float*)d_ws;
    float* ypad = xpad + XPAD_ELEMS;     // same footprint as rounds 1-13

    conv1_gelu<<<1024, 256, 0, stream>>>(input, w1, b1, xpad);
    kpn19<<<512, 1024, 0, stream>>>(xpad, kernel, ypad);
    conv2_sig<<<1024, 256, 0, stream>>>(ypad, w2, b2, out);
}

// Round 17
// 57.300 us; speedup vs baseline: 1.9116x; 1.0124x over previous
//
#include <hip/hip_runtime.h>
#include <math.h>

constexpr int B = 2, C = 16, H = 128, W = 128;
constexpr int HW = H * W;

// xpad: [B,16,146,148]; orig (h,w) -> (h+9, w+9); pads zeroed by conv1
constexpr int XR = 146, XS = 148, XCH = XR * XS;
constexpr size_t XPAD_ELEMS = (size_t)B * C * XCH;

// ypad: [B,16,130,136]; orig (h,w) -> (h+1, w+4); pads zeroed by kpn19
constexpr int YR = 130, YS = 136, YCH = YR * YS;

__device__ __forceinline__ float4 ld4(const float* p) { return *(const float4*)p; }

// ===========================================================================
// kpn19 (FROZEN r16): q-split + kv[19] kern batch + LDS x-staging.
// ===========================================================================
__global__ __launch_bounds__(1024) void kpn19(
    const float* __restrict__ xpad,  // [B,16,146,148]
    const float* __restrict__ kern,  // [B,361,128,128]
    float* __restrict__ ypad)        // [B,16,130,136]
{
    __shared__ __align__(16) float xls[4][2][16][84];   // 43,008 B
    __shared__ float red[3][16][64];                    // 12,288 B

    int tid  = threadIdx.x;
    int lane = tid & 63;
    int wq   = (tid >> 6) & 3;       // wave within q == channel group
    int q    = tid >> 8;             // kh-quarter, wave-uniform
    int blk  = blockIdx.x;           // 512 = wb2 x h128 x b2
    int wb   = blk & 1;
    int h    = (blk >> 1) & 127;
    int b    = blk >> 8;
    int px   = wb * 64 + lane;
    int c0   = wq * 4;

    // ---- ypad pad zeroing (replaces memset) ----
    if (tid < 64) {
        int pl = tid >> 2, i = tid & 3;
        int col = wb ? 132 + i : i;
        ypad[((size_t)(b * C + pl) * YR + (h + 1)) * YS + col] = 0.f;
    }
    if (h == 0 || h == 127) {
        int r = (h == 0) ? 0 : 129;
        for (int f = tid; f < 1088; f += 1024) {
            int pl = f / 68, col = wb * 68 + f % 68;
            ypad[((size_t)(b * C + pl) * YR + r) * YS + col] = 0.f;
        }
    }

    // ---- x staging sources: q-group covers 336 chunks = [16 ch][21 col4] ----
    int idx = tid & 255;
    int ma  = idx;
    int mb  = idx + 256;
    bool vb = (mb < 336);
    int ca  = ma / 21, cola = ma % 21;
    int cb  = vb ? mb / 21 : 0, colb = vb ? mb % 21 : 0;
    int kh0 = q * 5;
    int nkh = (q == 3) ? 4 : 5;

    const float* sa = xpad + (size_t)(b * C + ca) * XCH
                      + (size_t)(h + kh0) * XS + wb * 64 + cola * 4;
    const float* sb = xpad + (size_t)(b * C + cb) * XCH
                      + (size_t)(h + kh0) * XS + wb * 64 + colb * 4;

    const float* kp = kern + (size_t)b * 361 * HW + (size_t)h * W + px;

    float a0 = 0.f, a1 = 0.f, a2 = 0.f, a3 = 0.f;

#define STAGE(bufsel)                                                         \
    {                                                                         \
        __builtin_amdgcn_global_load_lds((const void*)sa,                     \
            (void*)(&xls[q][bufsel][0][0] + wq * 256), 16, 0, 0);             \
        if (vb)                                                               \
            __builtin_amdgcn_global_load_lds((const void*)sb,                 \
                (void*)(&xls[q][bufsel][0][0] + 1024 + wq * 256), 16, 0, 0);  \
        sa += XS; sb += XS;                                                   \
    }

    STAGE(0);
    asm volatile("s_waitcnt vmcnt(0)" ::: "memory");
    __syncthreads();

    #pragma unroll
    for (int r = 0; r < 5; ++r) {
        const int cur = r & 1;
        if (r + 1 < nkh) STAGE(cur ^ 1);
        if (r < nkh) {
            int kh = kh0 + r;
            float kv[19];
            const float* kpr = kp + (size_t)(kh * 19) * HW;
            #pragma unroll
            for (int kw = 0; kw < 19; ++kw)
                kv[kw] = kpr[(size_t)kw * HW];
            __builtin_amdgcn_sched_barrier(0);
            #pragma unroll
            for (int kw = 0; kw < 19; ++kw) {
                float k = kv[kw];
                a0 = fmaf(xls[q][cur][c0 + 0][lane + kw], k, a0);
                a1 = fmaf(xls[q][cur][c0 + 1][lane + kw], k, a1);
                a2 = fmaf(xls[q][cur][c0 + 2][lane + kw], k, a2);
                a3 = fmaf(xls[q][cur][c0 + 3][lane + kw], k, a3);
            }
        }
        asm volatile("s_waitcnt vmcnt(0)" ::: "memory");
        __syncthreads();
    }
#undef STAGE

    if (q > 0) {
        red[q - 1][c0 + 0][lane] = a0;
        red[q - 1][c0 + 1][lane] = a1;
        red[q - 1][c0 + 2][lane] = a2;
        red[q - 1][c0 + 3][lane] = a3;
    }
    __syncthreads();
    if (q == 0) {
        #pragma unroll
        for (int j = 0; j < 3; ++j) {
            a0 += red[j][c0 + 0][lane];
            a1 += red[j][c0 + 1][lane];
            a2 += red[j][c0 + 2][lane];
            a3 += red[j][c0 + 3][lane];
        }
        float* yp = ypad + ((size_t)(b * C + c0) * YR + (h + 1)) * YS + (px + 4);
        yp[0]       = a0;
        yp[YCH]     = a1;
        yp[2 * YCH] = a2;
        yp[3 * YCH] = a3;
    }
}

// ===========================================================================
// conv1: 3x3 conv (pad 1) + exact GELU -> xpad. r13's LDS-staged structure
// (proven correct) with the spill cause removed: ic loop NOT unrolled
// (#pragma unroll 1) -> per-ic t[9] ds_read batch + 36 FMAs, VGPR ~60.
// Thread = 1 px x 4 oc. Block = 128 px x 2 ocg; grid = half2 x h128 x b2.
// ===========================================================================
__global__ __launch_bounds__(256) void conv1_gelu(
    const float* __restrict__ in, const float* __restrict__ w1,
    const float* __restrict__ b1, float* __restrict__ xpad)
{
    __shared__ float ws[2304];
    __shared__ float bs[16];
    __shared__ __align__(16) float xs[16][3][128];   // 24 KB

    int tid = threadIdx.x;
    for (int i = tid; i < 2304; i += 256) ws[i] = w1[i];
    if (tid < 16) bs[tid] = b1[tid];

    int px  = tid & 127;
    int ocg = tid >> 7;                  // wave-uniform
    int blk = blockIdx.x;                // 512 = half2 x h128 x b2
    int half = blk & 1;
    int h   = (blk >> 1) & 127;
    int b   = blk >> 8;
    int oc0 = half * 8 + ocg * 4;

    // ---- xpad pad zeroing for the 8 planes this block owns ----
    if (tid < 160) {
        int j = tid / 20, i = tid % 20;
        int col = (i < 9) ? i : 128 + i;             // 0..8, 137..147
        xpad[((size_t)(b * C + half * 8 + j) * XR + (h + 9)) * XS + col] = 0.f;
    }
    if (h == 0 || h == 127) {
        int r0 = (h == 0) ? 0 : 137;
        for (int f = tid; f < 8 * 9 * XS; f += 256) {
            int j = f / (9 * XS), rem = f % (9 * XS);
            int r = r0 + rem / XS, col = rem % XS;
            xpad[((size_t)(b * C + half * 8 + j) * XR + r) * XS + col] = 0.f;
        }
    }

    // ---- stage rows h-1..h+1 x 16 ic into LDS (coalesced float4) ----
    const float4 z4 = make_float4(0.f, 0.f, 0.f, 0.f);
    #pragma unroll
    for (int j = 0; j < 6; ++j) {
        int m = tid + j * 256;           // < 1536
        int ic = m / 96, rem = m - ic * 96, r = rem >> 5, qq = rem & 31;
        int row = h + r - 1;
        float4 v = ((unsigned)row < 128u)
                 ? ld4(in + ((size_t)(b * C + ic) * H + row) * W + qq * 4) : z4;
        *(float4*)&xs[ic][r][qq * 4] = v;
    }
    __syncthreads();

    bool wm = (px > 0), wp = (px < 127);
    float a0 = 0.f, a1 = 0.f, a2 = 0.f, a3 = 0.f;

    #pragma unroll 1
    for (int ic = 0; ic < 16; ++ic) {
        float t[9];
        #pragma unroll
        for (int r = 0; r < 3; ++r) {
            t[r * 3 + 0] = wm ? xs[ic][r][px - 1] : 0.f;
            t[r * 3 + 1] = xs[ic][r][px];
            t[r * 3 + 2] = wp ? xs[ic][r][px + 1] : 0.f;
        }
        #pragma unroll
        for (int j = 0; j < 4; ++j) {
            const float* wp9 = ws + (oc0 + j) * 144 + ic * 9;
            float s = fmaf(wp9[0], t[0], fmaf(wp9[1], t[1], fmaf(wp9[2], t[2],
                      fmaf(wp9[3], t[3], fmaf(wp9[4], t[4], fmaf(wp9[5], t[5],
                      fmaf(wp9[6], t[6], fmaf(wp9[7], t[7], wp9[8] * t[8]))))))));
            if (j == 0) a0 += s; else if (j == 1) a1 += s;
            else if (j == 2) a2 += s; else a3 += s;
        }
    }

    float* xp = xpad + ((size_t)(b * C + oc0) * XR + (h + 9)) * XS + (px + 9);
    float v;
    v = a0 + bs[oc0 + 0]; xp[0]       = 0.5f * v * (1.0f + erff(v * 0.70710678f));
    v = a1 + bs[oc0 + 1]; xp[XCH]     = 0.5f * v * (1.0f + erff(v * 0.70710678f));
    v = a2 + bs[oc0 + 2]; xp[2 * XCH] = 0.5f * v * (1.0f + erff(v * 0.70710678f));
    v = a3 + bs[oc0 + 3]; xp[3 * XCH] = 0.5f * v * (1.0f + erff(v * 0.70710678f));
}

// ===========================================================================
// conv2: 3x3 conv (pad 1) + sigmoid -> out. r13 LDS-staged structure with
// #pragma unroll 1 on ic (spill fix). Padded-y input -> unconditional taps.
// ===========================================================================
__global__ __launch_bounds__(256) void conv2_sig(
    const float* __restrict__ ypad, const float* __restrict__ w2,
    const float* __restrict__ b2, float* __restrict__ out)
{
    __shared__ float ws[2304];
    __shared__ float bs[16];
    __shared__ __align__(16) float ys[16][3][136];   // 26.1 KB

    int tid = threadIdx.x;
    for (int i = tid; i < 2304; i += 256) ws[i] = w2[i];
    if (tid < 16) bs[tid] = b2[tid];

    int px  = tid & 127;
    int ocg = tid >> 7;
    int blk = blockIdx.x;                // 512 = half2 x h128 x b2
    int half = blk & 1;
    int h   = (blk >> 1) & 127;
    int b   = blk >> 8;
    int oc0 = half * 8 + ocg * 4;

    // stage padded rows h..h+2 x 16 ic, cols 0..135
    #pragma unroll
    for (int j = 0; j < 7; ++j) {
        int m = tid + j * 256;
        if (m < 1632) {
            int ic = m / 102, rem = m - ic * 102, r = rem / 34, qq = rem % 34;
            float4 v = ld4(ypad + ((size_t)(b * C + ic) * YR + (h + r)) * YS + qq * 4);
            *(float4*)&ys[ic][r][qq * 4] = v;
        }
    }
    __syncthreads();

    float a0 = 0.f, a1 = 0.f, a2 = 0.f, a3 = 0.f;

    #pragma unroll 1
    for (int ic = 0; ic < 16; ++ic) {
        float t[9];
        #pragma unroll
        for (int r = 0; r < 3; ++r) {
            t[r * 3 + 0] = ys[ic][r][px + 3];
            t[r * 3 + 1] = ys[ic][r][px + 4];
            t[r * 3 + 2] = ys[ic][r][px + 5];
        }
        #pragma unroll
        for (int j = 0; j < 4; ++j) {
            const float* wp9 = ws + (oc0 + j) * 144 + ic * 9;
            float s = fmaf(wp9[0], t[0], fmaf(wp9[1], t[1], fmaf(wp9[2], t[2],
                      fmaf(wp9[3], t[3], fmaf(wp9[4], t[4], fmaf(wp9[5], t[5],
                      fmaf(wp9[6], t[6], fmaf(wp9[7], t[7], wp9[8] * t[8]))))))));
            if (j == 0) a0 += s; else if (j == 1) a1 += s;
            else if (j == 2) a2 += s; else a3 += s;
        }
    }

    float* op = out + ((size_t)(b * C + oc0) * H + h) * W + px;
    float v;
    v = a0 + bs[oc0 + 0]; op[0]      = 1.0f / (1.0f + expf(-v));
    v = a1 + bs[oc0 + 1]; op[HW]     = 1.0f / (1.0f + expf(-v));
    v = a2 + bs[oc0 + 2]; op[2 * HW] = 1.0f / (1.0f + expf(-v));
    v = a3 + bs[oc0 + 3]; op[3 * HW] = 1.0f / (1.0f + expf(-v));
}

// ---------------------------------------------------------------------------
extern "C" void kernel_launch(void* const* d_in, const int* in_sizes, int n_in,
                              void* d_out, int out_size, void* d_ws, size_t ws_size,
                              hipStream_t stream)
{
    const float* input  = (const float*)d_in[0];
    const float* kernel = (const float*)d_in[1];
    const float* w1     = (const float*)d_in[2];
    const float* b1     = (const float*)d_in[3];
    const float* w2     = (const float*)d_in[4];
    const float* b2     = (const float*)d_in[5];
    float* out = (float*)d_out;

    float* xpad = (float*)d_ws;
    float* ypad = xpad + XPAD_ELEMS;

    conv1_gelu<<<512, 256, 0, stream>>>(input, w1, b1, xpad);
    kpn19<<<512, 1024, 0, stream>>>(xpad, kernel, ypad);
    conv2_sig<<<512, 256, 0, stream>>>(ypad, w2, b2, out);
}